// Round 16
// baseline (38.475 us; speedup 1.0000x reference)
//
#include <hip/hip_runtime.h>

// OuterProductMean on MI355X (gfx950) -- SINGLE fused kernel.
// out[i,j,p] = b2[p] + sum_{c,d} W2[p, c*32+d] * x[i,d] * x[j,c],  x = seq@W1^T + b1.
// Factored: Y[i][c][p] = sum_d W2[p][c*32+d] * x[i][d]  (f16, 2 MB scratch)
//           out[i,j,p] = b2[p] + sum_c x[j,c] * Y[i][c][p]
// ONE kernel, grid 256 x 256 thr (1 block/CU; LDS 59.5KB < 160KB => all blocks
// co-resident by capacity, no dispatch-order dependence). Per block:
//   front: R15-proven all-MFMA x + Y for tile (ibase, c)   [LDS overlay 1]
//   flag:  __syncthreads (drain stores) -> release atomicAdd; acquire-spin 256
//   outer: R15-proven MFMA + wave-private transpose epilogue, 8 i-tiles at
//          fixed q, xbs staged once, ybs dbuf per wave-pair [LDS overlay 2]
// Removes one graph node + dependency gap (~4-6us of launch/ramp/drain).
// Floor: 67 MB output write ~10.6 us.

static constexpr int LL  = 512;
static constexpr int IND = 256;
static constexpr int DM  = 32;   // DIM_MSA
static constexpr int PD  = 64;   // PAIR_DIM

typedef _Float16 f16x4 __attribute__((ext_vector_type(4)));
typedef _Float16 f16x8 __attribute__((ext_vector_type(8)));
typedef float    f32x16 __attribute__((ext_vector_type(16)));

#define LGKM_BARRIER() do { \
    asm volatile("s_waitcnt lgkmcnt(0)" ::: "memory"); \
    __builtin_amdgcn_s_barrier(); \
  } while (0)

__device__ __forceinline__ f16x4 cvt4(const float4 v) {
  f16x4 r;
  r[0] = (_Float16)v.x; r[1] = (_Float16)v.y;
  r[2] = (_Float16)v.z; r[3] = (_Float16)v.w;
  return r;
}

static constexpr int SP = 264;  // f16 stride for seq/W1 staging (33x16B)
static constexpr int XP = 40;   // f16 stride for x/W2 tiles
static constexpr int XPAD = 40; // f16 stride for xbs (outer)

// LDS overlay offsets (bytes), all 16-aligned.
//  front: seqs 0..33792 | w1s ..50688 | w2h ..55808 | xh ..60928
//  outer: xbs 0..10240 | ybsA ..18432 | ybsB ..26624 | obuf ..43008
static constexpr int SMEM_BYTES = 60928;

__global__ __launch_bounds__(256) void k_fused(const float* __restrict__ seq,
                                               const float* __restrict__ W1,
                                               const float* __restrict__ b1,
                                               const float* __restrict__ W2,
                                               const float* __restrict__ b2,
                                               _Float16* __restrict__ xgh,
                                               _Float16* __restrict__ Ygh,
                                               unsigned int* __restrict__ flag,
                                               float* __restrict__ out) {
  __shared__ __align__(16) char smem[SMEM_BYTES];
  const int bid = blockIdx.x;
  const int t   = threadIdx.x;
  const int w   = t >> 6, lane = t & 63, l31 = lane & 31, lh = lane >> 5;

  // ================= FRONT (R15-proven, verbatim math) =================
  {
    _Float16* seqs = (_Float16*)(smem);
    _Float16* w1s  = (_Float16*)(smem + 33792);
    _Float16* w2h  = (_Float16*)(smem + 50688);
    _Float16* xh   = (_Float16*)(smem + 55808);
    const int c     = bid & 31;
    const int ibase = (bid >> 5) * 64;

    // stage seq chunk [64][256] -> f16 (coalesced)
#pragma unroll
    for (int k = 0; k < 16; ++k) {
      const int f = t + k * 256;
      const int row = f >> 6, c4 = f & 63;
      const float4 v = *(const float4*)(seq + (size_t)(ibase + row) * IND + c4 * 4);
      *(f16x4*)&seqs[row * SP + c4 * 4] = cvt4(v);
    }
    // stage W1 [32][256] -> f16
#pragma unroll
    for (int k = 0; k < 8; ++k) {
      const int f = t + k * 256;
      const int row = f >> 6, c4 = f & 63;
      const float4 v = *(const float4*)(W1 + (size_t)row * IND + c4 * 4);
      *(f16x4*)&w1s[row * SP + c4 * 4] = cvt4(v);
    }
    // stage W2 slice [64 p][32 d] -> f16, stride 40
#pragma unroll
    for (int k = 0; k < 2; ++k) {
      const int idx = t + k * 256;
      const int p = idx >> 3, d4 = idx & 7;
      const float4 v = *(const float4*)(W2 + (size_t)p * (DM * DM) + c * DM + d4 * 4);
      *(f16x4*)&w2h[p * XP + d4 * 4] = cvt4(v);
    }
    __syncthreads();

    // phase A (waves 0,1): x[ibase + w*32 .. +32][0..32], 16 chained MFMAs
    if (w < 2) {
      const _Float16* arow = &seqs[(w * 32 + l31) * SP + lh * 8];
      const _Float16* brow = &w1s[l31 * SP + lh * 8];
      f32x16 acc = {};
#pragma unroll
      for (int ks = 0; ks < 16; ++ks) {
        const f16x8 af = *(const f16x8*)(arow + ks * 16);
        const f16x8 bf = *(const f16x8*)(brow + ks * 16);
        acc = __builtin_amdgcn_mfma_f32_32x32x16_f16(af, bf, acc, 0, 0, 0);
      }
      const float bias1 = b1[l31];
#pragma unroll
      for (int r = 0; r < 16; ++r) {
        const int mrow = w * 32 + (r & 3) + 8 * (r >> 2) + 4 * lh;
        const float v = acc[r] + bias1;
        xh[mrow * XP + l31] = (_Float16)v;
        if (c == 0) xgh[(size_t)(ibase + mrow) * DM + l31] = (_Float16)v;
      }
    }
    __syncthreads();

    // phase B (all 4 waves): Y[64 i][64 p] = xh @ w2h^T, one 32x32 tile/wave
    {
      const int ih = w >> 1, ph = w & 1;
      const _Float16* arow = &xh[(ih * 32 + l31) * XP + lh * 8];
      const _Float16* brow = &w2h[(ph * 32 + l31) * XP + lh * 8];
      f32x16 acc = {};
      const f16x8 a0 = *(const f16x8*)(arow);
      const f16x8 b0 = *(const f16x8*)(brow);
      acc = __builtin_amdgcn_mfma_f32_32x32x16_f16(a0, b0, acc, 0, 0, 0);
      const f16x8 a1 = *(const f16x8*)(arow + 16);
      const f16x8 b1f = *(const f16x8*)(brow + 16);
      acc = __builtin_amdgcn_mfma_f32_32x32x16_f16(a1, b1f, acc, 0, 0, 0);
      _Float16* ybase = Ygh + ((size_t)ibase * DM + c) * PD + ph * 32 + l31;
#pragma unroll
      for (int r = 0; r < 16; ++r) {
        const int irow = ih * 32 + (r & 3) + 8 * (r >> 2) + 4 * lh;
        ybase[(size_t)irow * (DM * PD)] = (_Float16)acc[r];
      }
    }
  }

  // ============== producer->consumer grid barrier (flags) ==============
  __syncthreads();   // drains each wave's vmcnt -> all Ygh/xgh stores complete
  if (t == 0) {
    __hip_atomic_fetch_add(flag, 1u, __ATOMIC_RELEASE, __HIP_MEMORY_SCOPE_AGENT);
    while (__hip_atomic_load(flag, __ATOMIC_ACQUIRE, __HIP_MEMORY_SCOPE_AGENT) < 256u)
      __builtin_amdgcn_s_sleep(8);
  }
  __syncthreads();

  // ================= OUTER (R15-proven structure, 8 tiles) =================
  {
    _Float16* xbs  = (_Float16*)(smem);           // [128][40]
    _Float16* ybsA = (_Float16*)(smem + 10240);   // 2 x 2048 f16
    _Float16* ybsB = (_Float16*)(smem + 18432);   // 2 x 2048 f16
    float*    obuf = (float*)(smem + 26624);      // 4 waves x 1024 f32

    const int q  = bid & 3;
    const int i0 = bid >> 2;          // 0..63
    const int wp = w >> 1;            // wave-pair: 0 -> A stream, 1 -> B stream
    const int ph = w & 1;             // p-half within pair
    const int pn = ph * 32 + l31;
    const int grp = t >> 7;           // staging group == wp for this thread
    const int tt  = t & 127;
    float* const obufW = obuf + w * 1024;
    const float4 bias4 = *(const float4*)(b2 + ph * 32 + (lane & 7) * 4);
    _Float16* const myYbs = grp ? ybsB : ybsA;
    const int mybase = i0 + 64 * wp;  // tile at step s: mybase + 128*s

    // stage xbs: [128 j][32 c], 32B per thread, coalesced
    {
      const int row = t >> 1, half = t & 1;
      const f16x8* src = (const f16x8*)(xgh + (size_t)(q * 128 + row) * DM + half * 16);
      _Float16* dst = xbs + row * XPAD + half * 16;
      *(f16x8*)(dst)     = src[0];
      *(f16x8*)(dst + 8) = src[1];
    }
    // stage step-0 ybs for this group's stream (A: i0, B: i0+64)
    {
      const f16x8* ys = (const f16x8*)(Ygh + (size_t)(i0 + 64 * grp) * (DM * PD));
      *(f16x8*)&myYbs[tt * 8]        = ys[tt];
      *(f16x8*)&myYbs[1024 + tt * 8] = ys[128 + tt];
    }
    LGKM_BARRIER();

    auto process = [&](int i, const _Float16* __restrict__ yb) {
      f16x8 bf0, bf1;
#pragma unroll
      for (int e = 0; e < 8; ++e) {
        bf0[e] = yb[(lh * 8 + e) * PD + pn];
        bf1[e] = yb[(16 + lh * 8 + e) * PD + pn];
      }
      const size_t orow0 = ((size_t)i * LL + q * 128) * PD;
#pragma unroll
      for (int jt = 0; jt < 4; ++jt) {
        const int ai = (jt * 32 + l31) * XPAD + lh * 8;
        const f16x8 a0 = *(const f16x8*)&xbs[ai];
        const f16x8 a1 = *(const f16x8*)&xbs[ai + 16];
        f32x16 acc = {};
        acc = __builtin_amdgcn_mfma_f32_32x32x16_f16(a0, bf0, acc, 0, 0, 0);
        acc = __builtin_amdgcn_mfma_f32_32x32x16_f16(a1, bf1, acc, 0, 0, 0);
#pragma unroll
        for (int r = 0; r < 16; ++r) {
          const int row = (r & 3) + 8 * (r >> 2) + 4 * lh;
          obufW[row * 32 + l31] = acc[r];
        }
#pragma unroll
        for (int k = 0; k < 4; ++k) {
          const int idx = lane + k * 64;
          const int row = idx >> 3, pseg = idx & 7;
          float4 v = *(const float4*)&obufW[idx * 4];
          v.x += bias4.x; v.y += bias4.y; v.z += bias4.z; v.w += bias4.w;
          *(float4*)(out + orow0 + (size_t)(jt * 32 + row) * PD + ph * 32 + pseg * 4) = v;
        }
      }
    };

    f16x8 n0, n1;
    // prefetch step 1
    {
      const f16x8* ys = (const f16x8*)(Ygh + (size_t)(mybase + 128) * (DM * PD));
      n0 = ys[tt]; n1 = ys[128 + tt];
    }
    process(mybase, myYbs);                      // step 0 (buf 0)
    *(f16x8*)&myYbs[2048 + tt * 8]        = n0;  // commit step 1 (buf 1)
    *(f16x8*)&myYbs[2048 + 1024 + tt * 8] = n1;
    LGKM_BARRIER();
    {
      const f16x8* ys = (const f16x8*)(Ygh + (size_t)(mybase + 256) * (DM * PD));
      n0 = ys[tt]; n1 = ys[128 + tt];
    }
    process(mybase + 128, myYbs + 2048);         // step 1 (buf 1)
    *(f16x8*)&myYbs[tt * 8]        = n0;         // commit step 2 (buf 0)
    *(f16x8*)&myYbs[1024 + tt * 8] = n1;
    LGKM_BARRIER();
    {
      const f16x8* ys = (const f16x8*)(Ygh + (size_t)(mybase + 384) * (DM * PD));
      n0 = ys[tt]; n1 = ys[128 + tt];
    }
    process(mybase + 256, myYbs);                // step 2 (buf 0)
    *(f16x8*)&myYbs[2048 + tt * 8]        = n0;  // commit step 3 (buf 1)
    *(f16x8*)&myYbs[2048 + 1024 + tt * 8] = n1;
    LGKM_BARRIER();
    process(mybase + 384, myYbs + 2048);         // step 3 (buf 1)
  }
}

extern "C" void kernel_launch(void* const* d_in, const int* in_sizes, int n_in,
                              void* d_out, int out_size, void* d_ws, size_t ws_size,
                              hipStream_t stream) {
  const float* seq = (const float*)d_in[0];
  const float* W1  = (const float*)d_in[1];
  const float* b1  = (const float*)d_in[2];
  const float* W2  = (const float*)d_in[3];
  const float* b2  = (const float*)d_in[4];
  float* out = (float*)d_out;

  // ws layout: xgh f16[512*32] (32KB) | Ygh f16[512*2048] (2MB) | flag u32
  _Float16* xgh = (_Float16*)d_ws;
  _Float16* Ygh = xgh + LL * DM;
  unsigned int* flag = (unsigned int*)((char*)d_ws + (size_t)LL * DM * 2 +
                                       (size_t)LL * DM * PD * 2);

  hipMemsetAsync(flag, 0, sizeof(unsigned int), stream);  // reset per replay
  k_fused<<<256, 256, 0, stream>>>(seq, W1, b1, W2, b2, xgh, Ygh, flag, out);
}

// Round 17
// 22.499 us; speedup vs baseline: 1.7101x; 1.7101x over previous
//
#include <hip/hip_runtime.h>

// OuterProductMean on MI355X (gfx950).
// out[i,j,p] = b2[p] + sum_{c,d} W2[p, c*32+d] * x[i,d] * x[j,c],  x = seq@W1^T + b1.
// Factored: Y[i][c][p] = sum_d W2[p][c*32+d] * x[i][d]  (f16, 2 MB scratch)
//           out[i,j,p] = b2[p] + sum_c x[j,c] * Y[i][c][p]
// TWO kernels (R15 verbatim -- best measured 22.35us):
//  k_front: ALL-MFMA. Phase A: x = seq@W1^T (LDS-staged frags).
//           Phase B: Y = x@W2slice^T as 8 mfma across 4 waves.
//  k_outer: MFMA + wave-private transpose epilogue, dense dwordx4 stores,
//           lgkm-only barriers, Y double-buffer. 4 blk/CU x 2 waves = the TLP
//           that hides stage/ramp -- R16's 1-blk/CU fusion regressed 16us.
// Floor: 67 MB output write ~10.6 us.

static constexpr int LL  = 512;
static constexpr int IND = 256;
static constexpr int DM  = 32;   // DIM_MSA
static constexpr int PD  = 64;   // PAIR_DIM

typedef _Float16 f16x4 __attribute__((ext_vector_type(4)));
typedef _Float16 f16x8 __attribute__((ext_vector_type(8)));
typedef float    f32x16 __attribute__((ext_vector_type(16)));

// LDS-only barrier: order ds ops across waves WITHOUT draining global stores.
#define LGKM_BARRIER() do { \
    asm volatile("s_waitcnt lgkmcnt(0)" ::: "memory"); \
    __builtin_amdgcn_s_barrier(); \
  } while (0)

__device__ __forceinline__ f16x4 cvt4(const float4 v) {
  f16x4 r;
  r[0] = (_Float16)v.x; r[1] = (_Float16)v.y;
  r[2] = (_Float16)v.z; r[3] = (_Float16)v.w;
  return r;
}

// ---------------- k_front: fused proj1 (MFMA) + Y (MFMA).
// Grid 256 = (8 i-chunks of 64 rows) x (32 c). 256 threads.
// Frag mapping (mfma_f32_32x32x16_f16, verified R6/R11/R13):
//   A[m][k]: m=lane&31, k=ks*16+(lane>>5)*8+e   (row-contiguous LDS read)
//   B[k][n]: n=lane&31, same k                  (row-contiguous LDS read)
//   D: col(n)=lane&31, row(m)=(r&3)+8*(r>>2)+4*(lane>>5)
static constexpr int SP = 264;  // f16 stride for seq/W1 staging (33x16B)
static constexpr int XP = 40;   // f16 stride for x/W2 tiles (k_outer-proven)

__global__ __launch_bounds__(256) void k_front(const float* __restrict__ seq,
                                               const float* __restrict__ W1,
                                               const float* __restrict__ b1,
                                               const float* __restrict__ W2,
                                               _Float16* __restrict__ xgh,
                                               _Float16* __restrict__ Ygh) {
  __shared__ __align__(16) _Float16 seqs[64 * SP];  // 33 KB
  __shared__ __align__(16) _Float16 w1s[32 * SP];   // 16.5 KB
  __shared__ __align__(16) _Float16 w2h[64 * XP];   //  5 KB  [p][d]
  __shared__ __align__(16) _Float16 xh[64 * XP];    //  5 KB  [i][d]
  const int c     = blockIdx.x & 31;
  const int ibase = (blockIdx.x >> 5) * 64;
  const int t     = threadIdx.x;

  // stage seq chunk [64][256] -> f16 (coalesced)
#pragma unroll
  for (int k = 0; k < 16; ++k) {
    const int f = t + k * 256;            // float4 idx over 64x64
    const int row = f >> 6, c4 = f & 63;
    const float4 v = *(const float4*)(seq + (size_t)(ibase + row) * IND + c4 * 4);
    *(f16x4*)&seqs[row * SP + c4 * 4] = cvt4(v);
  }
  // stage W1 [32][256] -> f16
#pragma unroll
  for (int k = 0; k < 8; ++k) {
    const int f = t + k * 256;
    const int row = f >> 6, c4 = f & 63;
    const float4 v = *(const float4*)(W1 + (size_t)row * IND + c4 * 4);
    *(f16x4*)&w1s[row * SP + c4 * 4] = cvt4(v);
  }
  // stage W2 slice [64 p][32 d] -> f16, stride 40
#pragma unroll
  for (int k = 0; k < 2; ++k) {
    const int idx = t + k * 256;          // 0..511 float4s
    const int p = idx >> 3, d4 = idx & 7;
    const float4 v = *(const float4*)(W2 + (size_t)p * (DM * DM) + c * DM + d4 * 4);
    *(f16x4*)&w2h[p * XP + d4 * 4] = cvt4(v);
  }
  __syncthreads();

  const int w = t >> 6, lane = t & 63, l31 = lane & 31, lh = lane >> 5;

  // phase A (waves 0,1): x[ibase + w*32 .. +32][0..32] via 16 chained MFMAs.
  if (w < 2) {
    const _Float16* arow = &seqs[(w * 32 + l31) * SP + lh * 8];
    const _Float16* brow = &w1s[l31 * SP + lh * 8];
    f32x16 acc = {};
#pragma unroll
    for (int ks = 0; ks < 16; ++ks) {
      const f16x8 af = *(const f16x8*)(arow + ks * 16);
      const f16x8 bf = *(const f16x8*)(brow + ks * 16);
      acc = __builtin_amdgcn_mfma_f32_32x32x16_f16(af, bf, acc, 0, 0, 0);
    }
    const float bias1 = b1[l31];
#pragma unroll
    for (int r = 0; r < 16; ++r) {
      const int mrow = w * 32 + (r & 3) + 8 * (r >> 2) + 4 * lh;
      const float v = acc[r] + bias1;
      xh[mrow * XP + l31] = (_Float16)v;                 // u16 scatter, cheap
      if (c == 0) xgh[(size_t)(ibase + mrow) * DM + l31] = (_Float16)v;
    }
  }
  __syncthreads();

  // phase B (all 4 waves): Y[64 i][64 p] = xh[64][32] @ w2h[64][32]^T
  // wave w -> (ih = w>>1, ph = w&1): one 32x32 tile, K=32 as 2 chained MFMAs.
  {
    const int ih = w >> 1, ph = w & 1;
    const _Float16* arow = &xh[(ih * 32 + l31) * XP + lh * 8];
    const _Float16* brow = &w2h[(ph * 32 + l31) * XP + lh * 8];
    f32x16 acc = {};
    {
      const f16x8 a0 = *(const f16x8*)(arow);
      const f16x8 b0 = *(const f16x8*)(brow);
      acc = __builtin_amdgcn_mfma_f32_32x32x16_f16(a0, b0, acc, 0, 0, 0);
      const f16x8 a1 = *(const f16x8*)(arow + 16);
      const f16x8 b1 = *(const f16x8*)(brow + 16);
      acc = __builtin_amdgcn_mfma_f32_32x32x16_f16(a1, b1, acc, 0, 0, 0);
    }
    // D: col(p)=l31, row(i)=(r&3)+8*(r>>2)+4*lh. Store f16 to Ygh[i][c][p].
    _Float16* ybase = Ygh + ((size_t)ibase * DM + c) * PD + ph * 32 + l31;
#pragma unroll
    for (int r = 0; r < 16; ++r) {
      const int irow = ih * 32 + (r & 3) + 8 * (r >> 2) + 4 * lh;
      ybase[(size_t)irow * (DM * PD)] = (_Float16)acc[r];  // 2x64B seg / wave-inst
    }
  }
}

// ---------------- k_outer: MFMA + wave-private LDS-transpose epilogue.
// Block = 128 thr (2 waves), 2 i-tiles (i0, i0+256) x 128 j x 64 p.
// D layout: col(p)=lane&31, row(j)=(reg&3)+8*(reg>>2)+4*(lane>>5)  [verified R6].
static constexpr int XPAD = 40;  // f16 row stride 80B (16B-aligned b128 reads)

__global__ __launch_bounds__(128, 3) void k_outer(const _Float16* __restrict__ xgh,
                                                  const _Float16* __restrict__ Ygh,
                                                  const float* __restrict__ b2,
                                                  float* __restrict__ out) {
  __shared__ __align__(16) _Float16 xbs[128 * XPAD];  // 10 KB: [j_local][c]
  __shared__ __align__(16) _Float16 ybs[2 * DM * PD]; // 2 x 4 KB: [c][p]
  __shared__ __align__(16) float    obuf[2][32 * 32]; // per-wave 4 KB
  const int q  = blockIdx.x & 3;       // j-quarter
  const int i0 = blockIdx.x >> 2;      // first i; second is i0+256
  const int t  = threadIdx.x;

  const int lane = t & 63;
  const int w    = t >> 6;        // p-half (0/1)
  const int l31  = lane & 31;
  const int lh   = lane >> 5;
  const int pn   = w * 32 + l31;  // this lane's p (n index)
  float* const obufW = &obuf[w][0];
  const float4 bias4 = *(const float4*)(b2 + w * 32 + (lane & 7) * 4);

  // stage x rows (row j = t): 64B per thread, coalesced; q-dependent only
  {
    const f16x8* src = (const f16x8*)(xgh + (size_t)(q * 128 + t) * DM);
    _Float16* dst = &xbs[t * XPAD];
    *(f16x8*)(dst)      = src[0];
    *(f16x8*)(dst + 8)  = src[1];
    *(f16x8*)(dst + 16) = src[2];
    *(f16x8*)(dst + 24) = src[3];
  }
  // stage Ygh[i0] into ybs[0]
  {
    const f16x8* ys = (const f16x8*)(Ygh + (size_t)i0 * (DM * PD));
    *(f16x8*)&ybs[t * 8]        = ys[t];
    *(f16x8*)&ybs[1024 + t * 8] = ys[128 + t];
  }
  LGKM_BARRIER();

  // issue-early: Ygh[i1] global loads in flight across tile-0 compute
  const f16x8* ys1 = (const f16x8*)(Ygh + (size_t)(i0 + 256) * (DM * PD));
  const f16x8 n0 = ys1[t];
  const f16x8 n1 = ys1[128 + t];

  auto process = [&](int i, const _Float16* __restrict__ yb) {
    // B frags: one-time scattered u16 gather (2-way bank alias = free)
    f16x8 b0, b1;
#pragma unroll
    for (int e = 0; e < 8; ++e) {
      b0[e] = yb[(lh * 8 + e) * PD + pn];
      b1[e] = yb[(16 + lh * 8 + e) * PD + pn];
    }
    const size_t orow0 = ((size_t)i * LL + q * 128) * PD;
#pragma unroll
    for (int jt = 0; jt < 4; ++jt) {
      const int ai = (jt * 32 + l31) * XPAD + lh * 8;
      const f16x8 a0 = *(const f16x8*)&xbs[ai];
      const f16x8 a1 = *(const f16x8*)&xbs[ai + 16];
      f32x16 acc = {};
      acc = __builtin_amdgcn_mfma_f32_32x32x16_f16(a0, b0, acc, 0, 0, 0);
      acc = __builtin_amdgcn_mfma_f32_32x32x16_f16(a1, b1, acc, 0, 0, 0);
      // wave-private transpose: scatter (banks = l31, 2-way max)
#pragma unroll
      for (int r = 0; r < 16; ++r) {
        const int row = (r & 3) + 8 * (r >> 2) + 4 * lh;  // j within subtile
        obufW[row * 32 + l31] = acc[r];
      }
      // intra-wave readback (compiler orders via lgkmcnt) + dense stores
#pragma unroll
      for (int k = 0; k < 4; ++k) {
        const int idx = lane + k * 64;           // float4 idx 0..255
        const int row = idx >> 3, pseg = idx & 7;
        float4 v = *(const float4*)&obufW[idx * 4];
        v.x += bias4.x; v.y += bias4.y; v.z += bias4.z; v.w += bias4.w;
        *(float4*)(out + orow0 + (size_t)(jt * 32 + row) * PD + w * 32 + pseg * 4) = v;
      }
    }
  };

  process(i0, ybs);

  // write-late: commit prefetched Y[i1]
  *(f16x8*)&ybs[2048 + t * 8]        = n0;
  *(f16x8*)&ybs[2048 + 1024 + t * 8] = n1;
  LGKM_BARRIER();

  process(i0 + 256, ybs + 2048);
}

extern "C" void kernel_launch(void* const* d_in, const int* in_sizes, int n_in,
                              void* d_out, int out_size, void* d_ws, size_t ws_size,
                              hipStream_t stream) {
  const float* seq = (const float*)d_in[0];
  const float* W1  = (const float*)d_in[1];
  const float* b1  = (const float*)d_in[2];
  const float* W2  = (const float*)d_in[3];
  const float* b2  = (const float*)d_in[4];
  float* out = (float*)d_out;

  // ws layout: xgh f16[512*32] | Ygh f16[512*32*64]  => ~2.1 MB
  _Float16* xgh = (_Float16*)d_ws;
  _Float16* Ygh = xgh + LL * DM;

  k_front<<<256, 256, 0, stream>>>(seq, W1, b1, W2, xgh, Ygh);
  k_outer<<<LL * 2, 128, 0, stream>>>(xgh, Ygh, b2, out);
}